// Round 2
// baseline (675.369 us; speedup 1.0000x reference)
//
#include <hip/hip_runtime.h>

typedef short short8 __attribute__((ext_vector_type(8)));
typedef short short4v __attribute__((ext_vector_type(4)));
typedef float f32x4 __attribute__((ext_vector_type(4)));

#define NT 550
#define NS 2209
#define NSP 2304
#define NP 12
#define NBK 69
#define NSTILE 18
#define GNRM 3.9894228040143f

typedef unsigned short bfu;

__device__ __forceinline__ bfu f2bf(float f) {
    unsigned int u = __float_as_uint(f);
    unsigned int r = (u + 0x7fffu + ((u >> 16) & 1u)) >> 16;
    return (bfu)r;
}

__device__ __forceinline__ float sigm(float x) {
    return __builtin_amdgcn_rcpf(1.0f + __expf(-x));
}

// ---------- weight conversion: fp32 -> transposed bf16 ----------
__global__ void k_prep(const float* __restrict__ W2, const float* __restrict__ W3,
                       const float* __restrict__ W4,
                       bfu* __restrict__ w2h, bfu* __restrict__ w3h, bfu* __restrict__ w4h) {
    int id = blockIdx.x * 256 + threadIdx.x;
    if (id < 8192) {                       // w2h[c][k]  c<128,k<64   from W2(64,128)
        int c = id >> 6, k = id & 63;
        w2h[id] = f2bf(W2[k * 128 + c]);
    } else if (id < 8192 + 32768) {        // w3h[c][k]  c<256,k<128  from W3(128,256)
        int j = id - 8192;
        int c = j >> 7, k = j & 127;
        w3h[j] = f2bf(W3[k * 256 + c]);
    } else {                               // w4h[s][k]  s<2304,k<256 from W4(256,2209)
        int j = id - 40960;
        int s = j >> 8, k = j & 255;
        w4h[j] = f2bf(s < NS ? W4[k * NS + s] : 0.0f);
    }
}

// ---------- bucketing ----------
__global__ void k_count(const float* __restrict__ el, int* __restrict__ counts) {
    int id = blockIdx.x * 256 + threadIdx.x;   // 32768 electrons flat
    float z = el[id * 3 + 2];
    int bk = (int)(z * 0.125f);
    bk = bk < 0 ? 0 : (bk > NBK - 1 ? NBK - 1 : bk);
    int b = id >> 13;
    atomicAdd(&counts[b * NBK + bk], 1);
}

__global__ void k_scan(const int* __restrict__ counts, int* __restrict__ offs) {
    if (threadIdx.x == 0 && blockIdx.x == 0) {
        int acc = 0;
        for (int i = 0; i < 4 * NBK; ++i) { offs[i] = acc; acc += counts[i]; }
    }
}

__global__ void k_scatter(const float* __restrict__ el, const int* __restrict__ offs,
                          int* __restrict__ cur, int* __restrict__ idxl) {
    int id = blockIdx.x * 256 + threadIdx.x;
    float z = el[id * 3 + 2];
    int bk = (int)(z * 0.125f);
    bk = bk < 0 ? 0 : (bk > NBK - 1 ? NBK - 1 : bk);
    int key = (id >> 13) * NBK + bk;
    int pos = offs[key] + atomicAdd(&cur[key], 1);
    idxl[pos] = id;
}

// ---------- phase A: MLP layers 1-3 (-> s3 bf16) + pmt path ----------
__global__ __launch_bounds__(256, 1) void k_mlp(
    const float* __restrict__ el, const float* __restrict__ wt,
    const float* __restrict__ Wp1, const float* __restrict__ bp1,
    const float* __restrict__ Wp2, const float* __restrict__ bp2,
    const float* __restrict__ psc,
    const float* __restrict__ Ws1, const float* __restrict__ bs1,
    const float* __restrict__ bs2, const float* __restrict__ bs3,
    const bfu* __restrict__ w2h, const bfu* __restrict__ w3h,
    bfu* __restrict__ s3h, float* __restrict__ outP) {

    __shared__ __align__(16) bfu bufA[32768];  // h1t[128][64] | w2t[128][64] | h2t[128][128]; reused as s3 stage [128][256]
    __shared__ __align__(16) bfu w3t[32768];   // [c=256][k=128] swz cpr16
    __shared__ float xyb[256];
    __shared__ float pwb[444];
    __shared__ float s1w[128];
    __shared__ float b1s[64], b2s[128], b3s[256];

    bfu* h1t = bufA;            // [n][64]  cpr8
    bfu* w2t = bufA + 8192;     // [c][64]  cpr8
    bfu* h2t = bufA + 16384;    // [n][128] cpr16

    const int tid = threadIdx.x;
    const int wv = tid >> 6, ln = tid & 63;
    const int e0 = blockIdx.x * 128;
    const int b = blockIdx.x >> 6;

    // FIX(R1): block has 256 threads; pwb has 444 entries -> strided load
    for (int i = tid; i < 444; i += 256)
        pwb[i] = (i < 56) ? Wp1[i] :
                 (i < 84) ? bp1[i - 56] :
                 (i < 420) ? Wp2[i - 84] :
                 (i < 432) ? bp2[i - 420] : psc[i - 432];
    if (tid < 128) s1w[tid] = Ws1[tid];
    if (tid < 64) b1s[tid] = bs1[tid];
    if (tid < 128) b2s[tid] = bs2[tid];
    b3s[tid] = bs3[tid];

    float x = 0.f, y = 0.f, z = 0.f, w = 0.f;
    if (tid < 128) {
        int e = e0 + tid;
        x = el[e * 3]; y = el[e * 3 + 1]; z = el[e * 3 + 2]; w = wt[e];
        xyb[tid * 2] = x; xyb[tid * 2 + 1] = y;
    }
    // stage w2t (swizzled)
    for (int i = 0; i < 4; ++i) {
        int cid = i * 256 + tid;
        int row = cid >> 3, c5 = cid & 7;
        short8 v = *(const short8*)(const void*)&w2h[row * 64 + c5 * 8];
        *(short8*)(void*)&w2t[row * 64 + ((c5 ^ (row & 7)) * 8)] = v;
    }
    // stage w3t (swizzled)
    for (int i = 0; i < 16; ++i) {
        int cid = i * 256 + tid;
        int row = cid >> 4, c5 = cid & 15;
        short8 v = *(const short8*)(const void*)&w3h[row * 128 + c5 * 8];
        *(short8*)(void*)&w3t[row * 128 + ((c5 ^ (row & 7)) * 8)] = v;
    }
    __syncthreads();

    // L1: h1 = sigm(xy@Ws1 + bs1), 2 threads per electron
    {
        int n = tid & 127;
        int j0 = (tid >> 7) * 32;
        float xx = xyb[n * 2], yy = xyb[n * 2 + 1];
        for (int jj = 0; jj < 32; ++jj) {
            int j = j0 + jj;
            float h = sigm(xx * s1w[j] + yy * s1w[64 + j] + b1s[j]);
            h1t[n * 64 + (((j >> 3) ^ (n & 7)) * 8) + (j & 7)] = f2bf(h);
        }
    }
    // pmt path, exact fp32 (threads 0..127)
    if (tid < 128) {
        float h[28];
        for (int j = 0; j < 28; ++j)
            h[j] = sigm(x * pwb[j] + y * pwb[28 + j] + pwb[56 + j]);
        float rp[12];
        for (int p = 0; p < 12; ++p) {
            float a = pwb[420 + p];
            for (int j = 0; j < 28; ++j) a += h[j] * pwb[84 + j * 12 + p];
            float sc = pwb[432 + p];
            rp[p] = sigm(a) * sc * sc;
        }
        int tz = (int)z;
        for (int k = -2; k <= 2; ++k) {
            int t = tz + k;
            if (t < 0 || t >= NT) continue;
            float d = (float)t + 0.5f - z;
            float g = w * GNRM * __expf(-10.0f * d * d);
            float* o = outP + (b * NP) * NT + t;
            for (int p = 0; p < NP; ++p) atomicAdd(o + p * NT, g * rp[p]);
        }
    }
    __syncthreads();

    // L2: (128x64)@(64x128) MFMA, wave = 64Mx64N quadrant
    {
        const int mr = (wv >> 1) * 64;
        const int nc = (wv & 1) * 64;
        f32x4 acc[4][4];
        for (int m = 0; m < 4; ++m) for (int nf = 0; nf < 4; ++nf) acc[m][nf] = (f32x4){0.f, 0.f, 0.f, 0.f};
        for (int kk = 0; kk < 2; ++kk) {
            int kc = kk * 4 + (ln >> 4);
            short8 af[4], bf[4];
            for (int m = 0; m < 4; ++m) {
                int row = mr + 16 * m + (ln & 15);
                af[m] = *(const short8*)(const void*)&h1t[row * 64 + ((kc ^ (row & 7)) * 8)];
            }
            for (int nf = 0; nf < 4; ++nf) {
                int c = nc + 16 * nf + (ln & 15);
                bf[nf] = *(const short8*)(const void*)&w2t[c * 64 + ((kc ^ (c & 7)) * 8)];
            }
            for (int m = 0; m < 4; ++m)
                for (int nf = 0; nf < 4; ++nf)
                    acc[m][nf] = __builtin_amdgcn_mfma_f32_16x16x32_bf16(af[m], bf[nf], acc[m][nf], 0, 0, 0);
        }
        for (int m = 0; m < 4; ++m)
            for (int nf = 0; nf < 4; ++nf) {
                int c = nc + 16 * nf + (ln & 15);
                float bb = b2s[c];
                for (int r = 0; r < 4; ++r) {
                    int n = mr + 16 * m + (ln >> 4) * 4 + r;
                    float hh = sigm(acc[m][nf][r] + bb);
                    h2t[n * 128 + (((c >> 3) ^ (n & 7)) * 8) + (c & 7)] = f2bf(hh);
                }
            }
    }
    __syncthreads();

    // L3: (128x128)@(128x256) MFMA, wave = 64Mx128N
    f32x4 acc3[4][8];
    const int mr3 = (wv >> 1) * 64;
    const int nc3 = (wv & 1) * 128;
    for (int m = 0; m < 4; ++m) for (int nf = 0; nf < 8; ++nf) acc3[m][nf] = (f32x4){0.f, 0.f, 0.f, 0.f};
    for (int kk = 0; kk < 4; ++kk) {
        int kc = kk * 4 + (ln >> 4);
        short8 af[4];
        for (int m = 0; m < 4; ++m) {
            int row = mr3 + 16 * m + (ln & 15);
            af[m] = *(const short8*)(const void*)&h2t[row * 128 + ((kc ^ (row & 7)) * 8)];
        }
        for (int nf = 0; nf < 8; ++nf) {
            int c = nc3 + 16 * nf + (ln & 15);
            short8 bf = *(const short8*)(const void*)&w3t[c * 128 + ((kc ^ (c & 7)) * 8)];
            for (int m = 0; m < 4; ++m)
                acc3[m][nf] = __builtin_amdgcn_mfma_f32_16x16x32_bf16(af[m], bf, acc3[m][nf], 0, 0, 0);
        }
    }
    __syncthreads();   // all LDS reads done before bufA is reused
    for (int m = 0; m < 4; ++m)
        for (int nf = 0; nf < 8; ++nf) {
            int c = nc3 + 16 * nf + (ln & 15);
            float bb = b3s[c];
            for (int r = 0; r < 4; ++r) {
                int n = mr3 + 16 * m + (ln >> 4) * 4 + r;
                float ss = sigm(acc3[m][nf][r] + bb);
                bufA[n * 256 + (((c >> 3) ^ (n & 7)) * 8) + (c & 7)] = f2bf(ss);
            }
        }
    __syncthreads();
    // coalesced copy-out (de-swizzled)
    for (int i = 0; i < 16; ++i) {
        int cid = i * 256 + tid;
        int row = cid >> 5, c5 = cid & 31;
        short8 v = *(const short8*)(const void*)&bufA[row * 256 + ((c5 ^ (row & 7)) * 8)];
        *(short8*)(void*)&s3h[(size_t)(e0 + row) * 256 + c5 * 8] = v;
    }
}

// ---------- phase B: big layer GEMM + gaussian scatter GEMM ----------
__global__ __launch_bounds__(256, 1) void k_sipm(
    const float* __restrict__ el, const float* __restrict__ wt,
    const float* __restrict__ bs4, const float* __restrict__ sis,
    const bfu* __restrict__ s3h, const bfu* __restrict__ w4h,
    const int* __restrict__ idxl, const int* __restrict__ counts,
    const int* __restrict__ offs, float* __restrict__ outS) {

    __shared__ __align__(16) bfu w4t[128 * 256];  // [s][k] cpr32
    __shared__ __align__(16) bfu s3t[64 * 256];   // [n][k] cpr32
    __shared__ __align__(16) bfu rpt[128 * 64];   // [s][n] cpr8
    __shared__ __align__(16) bfu Et[16 * 64];     // [t][n] cpr8
    __shared__ int idxb[64];
    __shared__ float zbv[64], wbv[64];
    __shared__ float bss[128], si2[128];

    const int tid = threadIdx.x;
    const int wv = tid >> 6, ln = tid & 63;
    const int bid = blockIdx.x;
    const int st = bid % NSTILE;
    const int bk = (bid / NSTILE) % NBK;
    const int b = bid / (NSTILE * NBK);
    const int key = b * NBK + bk;
    const int cnt = counts[key];
    if (cnt == 0) return;
    const int off = offs[key];
    const int s0 = st * 128;
    const int t0 = bk * 8;

    for (int i = 0; i < 16; ++i) {
        int cid = i * 256 + tid;
        int row = cid >> 5, c5 = cid & 31;
        short8 v = *(const short8*)(const void*)&w4h[(size_t)(s0 + row) * 256 + c5 * 8];
        *(short8*)(void*)&w4t[row * 256 + ((c5 ^ (row & 7)) * 8)] = v;
    }
    if (tid < 128) {
        int s = s0 + tid;
        bss[tid] = (s < NS) ? bs4[s] : 0.0f;
        float sc = (s < NS) ? sis[s] : 0.0f;
        si2[tid] = sc * sc;
    }

    const int nch = (cnt + 63) >> 6;
    for (int c = 0; c < nch; ++c) {
        __syncthreads();
        if (tid < 64) {
            int li = c * 64 + tid;
            int e = (li < cnt) ? idxl[off + li] : -1;
            idxb[tid] = e;
            zbv[tid] = (e >= 0) ? el[e * 3 + 2] : 0.0f;
            wbv[tid] = (e >= 0) ? wt[e] : 0.0f;
        }
        __syncthreads();
        for (int i = 0; i < 8; ++i) {       // stage s3 chunk (gather rows)
            int cid = i * 256 + tid;
            int row = cid >> 5, c5 = cid & 31;
            int e = idxb[row];
            const bfu* src = s3h + (size_t)((e >= 0) ? e : 0) * 256 + c5 * 8;
            short8 v = *(const short8*)(const void*)src;
            *(short8*)(void*)&s3t[row * 256 + ((c5 ^ (row & 7)) * 8)] = v;
        }
        for (int i = 0; i < 4; ++i) {       // build gaussian tile E[t][n]
            int id = i * 256 + tid;
            int j = id >> 6, n = id & 63;
            int tg = t0 - 4 + j;
            float d = (float)tg + 0.5f - zbv[n];
            float g = (tg >= 0 && tg < NT) ? wbv[n] * GNRM * __expf(-10.0f * d * d) : 0.0f;
            Et[j * 64 + (((n >> 3) ^ (j & 7)) * 8) + (n & 7)] = f2bf(g);
        }
        __syncthreads();

        // GEMM1: (64n x 256k) @ (256k x 128s), wave owns 32 s
        f32x4 acc[4][2];
        for (int m = 0; m < 4; ++m) for (int nf = 0; nf < 2; ++nf) acc[m][nf] = (f32x4){0.f, 0.f, 0.f, 0.f};
        for (int kk = 0; kk < 8; ++kk) {
            int kc = kk * 4 + (ln >> 4);
            short8 af[4], bf[2];
            for (int m = 0; m < 4; ++m) {
                int row = 16 * m + (ln & 15);
                af[m] = *(const short8*)(const void*)&s3t[row * 256 + ((kc ^ (row & 7)) * 8)];
            }
            for (int nf = 0; nf < 2; ++nf) {
                int sl = 32 * wv + 16 * nf + (ln & 15);
                bf[nf] = *(const short8*)(const void*)&w4t[sl * 256 + ((kc ^ (sl & 7)) * 8)];
            }
            for (int m = 0; m < 4; ++m)
                for (int nf = 0; nf < 2; ++nf)
                    acc[m][nf] = __builtin_amdgcn_mfma_f32_16x16x32_bf16(af[m], bf[nf], acc[m][nf], 0, 0, 0);
        }
        // sigmoid * si_scale^2 -> rpt[s][n]
        for (int nf = 0; nf < 2; ++nf) {
            int sl = 32 * wv + 16 * nf + (ln & 15);
            float bb = bss[sl], sc = si2[sl];
            for (int m = 0; m < 4; ++m) {
                short4v pk;
                for (int r = 0; r < 4; ++r)
                    pk[r] = (short)f2bf(sc * sigm(acc[m][nf][r] + bb));
                int n0 = 16 * m + (ln >> 4) * 4;
                *(short4v*)(void*)&rpt[sl * 64 + (((n0 >> 3) ^ (sl & 7)) * 8) + (n0 & 7)] = pk;
            }
        }
        __syncthreads();

        // GEMM2: out^T(16t x 128s) = E^T(16x64) @ rpt(64 x 128s)
        f32x4 a2[2];
        a2[0] = (f32x4){0.f, 0.f, 0.f, 0.f}; a2[1] = (f32x4){0.f, 0.f, 0.f, 0.f};
        for (int kk = 0; kk < 2; ++kk) {
            int kc = kk * 4 + (ln >> 4);
            int tr = ln & 15;
            short8 ea = *(const short8*)(const void*)&Et[tr * 64 + ((kc ^ (tr & 7)) * 8)];
            for (int nf = 0; nf < 2; ++nf) {
                int sl = 32 * wv + 16 * nf + (ln & 15);
                short8 bb = *(const short8*)(const void*)&rpt[sl * 64 + ((kc ^ (sl & 7)) * 8)];
                a2[nf] = __builtin_amdgcn_mfma_f32_16x16x32_bf16(ea, bb, a2[nf], 0, 0, 0);
            }
        }
        for (int nf = 0; nf < 2; ++nf) {
            int sl = 32 * wv + 16 * nf + (ln & 15);
            int s = s0 + sl;
            if (s >= NS) continue;
            for (int r = 0; r < 4; ++r) {
                int t = t0 - 4 + (ln >> 4) * 4 + r;
                if (t < 0 || t >= NT) continue;
                atomicAdd(&outS[((size_t)b * NS + s) * NT + t], a2[nf][r]);
            }
        }
    }
}

extern "C" void kernel_launch(void* const* d_in, const int* in_sizes, int n_in,
                              void* d_out, int out_size, void* d_ws, size_t ws_size,
                              hipStream_t stream) {
    const float* el  = (const float*)d_in[0];
    const float* wt  = (const float*)d_in[1];
    const float* Wp1 = (const float*)d_in[2];
    const float* bp1 = (const float*)d_in[3];
    const float* Wp2 = (const float*)d_in[4];
    const float* bp2 = (const float*)d_in[5];
    const float* psc = (const float*)d_in[6];
    const float* Ws1 = (const float*)d_in[7];
    const float* bs1 = (const float*)d_in[8];
    const float* Ws2 = (const float*)d_in[9];
    const float* bs2 = (const float*)d_in[10];
    const float* Ws3 = (const float*)d_in[11];
    const float* bs3 = (const float*)d_in[12];
    const float* Ws4 = (const float*)d_in[13];
    const float* bs4 = (const float*)d_in[14];
    const float* sis = (const float*)d_in[15];
    float* out = (float*)d_out;

    char* ws = (char*)d_ws;
    bfu* w2h     = (bfu*)(ws);
    bfu* w3h     = (bfu*)(ws + 16384);
    bfu* w4h     = (bfu*)(ws + 81920);
    bfu* s3h     = (bfu*)(ws + 1261568);
    int* counts  = (int*)(ws + 18038784);
    int* offs    = (int*)(ws + 18042880);
    int* cursors = (int*)(ws + 18046976);
    int* idxl    = (int*)(ws + 18051072);

    hipMemsetAsync(d_out, 0, (size_t)out_size * 4, stream);
    hipMemsetAsync(counts, 0, 4 * 4 * NBK, stream);
    hipMemsetAsync(cursors, 0, 4 * 4 * NBK, stream);

    k_prep<<<2464, 256, 0, stream>>>(Ws2, Ws3, Ws4, w2h, w3h, w4h);
    k_count<<<128, 256, 0, stream>>>(el, counts);
    k_scan<<<1, 64, 0, stream>>>(counts, offs);
    k_scatter<<<128, 256, 0, stream>>>(el, offs, cursors, idxl);
    k_mlp<<<256, 256, 0, stream>>>(el, wt, Wp1, bp1, Wp2, bp2, psc, Ws1, bs1, bs2, bs3,
                                   w2h, w3h, s3h, out);
    k_sipm<<<4 * NBK * NSTILE, 256, 0, stream>>>(el, wt, bs4, sis, s3h, w4h, idxl, counts, offs,
                                                 out + 4 * NP * NT);
}

// Round 4
// 398.860 us; speedup vs baseline: 1.6932x; 1.6932x over previous
//
#include <hip/hip_runtime.h>

typedef short short8 __attribute__((ext_vector_type(8)));
typedef short short4v __attribute__((ext_vector_type(4)));
typedef float f32x4 __attribute__((ext_vector_type(4)));

#define NT 550
#define NS 2209
#define NP 12
#define NBK 69
#define NSTILE 36
#define NGRP 9
#define GBK 8
#define GNRM 3.9894228040143f

typedef unsigned short bfu;

__device__ __forceinline__ bfu f2bf(float f) {
    unsigned int u = __float_as_uint(f);
    unsigned int r = (u + 0x7fffu + ((u >> 16) & 1u)) >> 16;
    return (bfu)r;
}

__device__ __forceinline__ float sigm(float x) {
    return __builtin_amdgcn_rcpf(1.0f + __expf(-x));
}

// ---------- weight conversion: fp32 -> transposed bf16 ----------
__global__ void k_prep(const float* __restrict__ W2, const float* __restrict__ W3,
                       const float* __restrict__ W4,
                       bfu* __restrict__ w2h, bfu* __restrict__ w3h, bfu* __restrict__ w4h) {
    int id = blockIdx.x * 256 + threadIdx.x;
    if (id < 8192) {                       // w2h[c][k]  c<128,k<64   from W2(64,128)
        int c = id >> 6, k = id & 63;
        w2h[id] = f2bf(W2[k * 128 + c]);
    } else if (id < 8192 + 32768) {        // w3h[c][k]  c<256,k<128  from W3(128,256)
        int j = id - 8192;
        int c = j >> 7, k = j & 127;
        w3h[j] = f2bf(W3[k * 256 + c]);
    } else {                               // w4h[s][k]  s<2304,k<256 from W4(256,2209)
        int j = id - 40960;
        int s = j >> 8, k = j & 255;
        w4h[j] = f2bf(s < NS ? W4[k * NS + s] : 0.0f);
    }
}

// ---------- bucketing (R2-proven) ----------
__global__ void k_count(const float* __restrict__ el, int* __restrict__ counts) {
    int id = blockIdx.x * 256 + threadIdx.x;
    float z = el[id * 3 + 2];
    int bk = (int)(z * 0.125f);
    bk = bk < 0 ? 0 : (bk > NBK - 1 ? NBK - 1 : bk);
    atomicAdd(&counts[(id >> 13) * NBK + bk], 1);
}

__global__ void k_scan(const int* __restrict__ counts, int* __restrict__ offs) {
    if (threadIdx.x == 0 && blockIdx.x == 0) {
        int acc = 0;
        for (int i = 0; i < 4 * NBK; ++i) { offs[i] = acc; acc += counts[i]; }
    }
}

__global__ void k_scatter(const float* __restrict__ el, const int* __restrict__ offs,
                          int* __restrict__ cur, int* __restrict__ idxl) {
    int id = blockIdx.x * 256 + threadIdx.x;
    float z = el[id * 3 + 2];
    int bk = (int)(z * 0.125f);
    bk = bk < 0 ? 0 : (bk > NBK - 1 ? NBK - 1 : bk);
    int key = (id >> 13) * NBK + bk;
    int pos = offs[key] + atomicAdd(&cur[key], 1);
    idxl[pos] = id;
}

// ---------- phase A: sipm MLP layers 1-3 -> s3h (linear, bf16) ----------
__global__ __launch_bounds__(256, 1) void k_mlp(
    const float* __restrict__ el,
    const float* __restrict__ Ws1, const float* __restrict__ bs1,
    const float* __restrict__ bs2, const float* __restrict__ bs3,
    const bfu* __restrict__ w2h, const bfu* __restrict__ w3h,
    bfu* __restrict__ s3h) {

    __shared__ __align__(16) bfu bufA[32768];  // h1t|w2t|h2t; reused as s3 stage [128][256]
    __shared__ __align__(16) bfu w3t[32768];   // [c=256][k=128] swz
    __shared__ float xyb[256];
    __shared__ float s1w[128];
    __shared__ float b1s[64], b2s[128], b3s[256];

    bfu* h1t = bufA;            // [n][64]
    bfu* w2t = bufA + 8192;     // [c][64]
    bfu* h2t = bufA + 16384;    // [n][128]

    const int tid = threadIdx.x;
    const int wv = tid >> 6, ln = tid & 63;
    const int e0 = blockIdx.x * 128;

    if (tid < 128) s1w[tid] = Ws1[tid];
    if (tid < 64) b1s[tid] = bs1[tid];
    if (tid < 128) b2s[tid] = bs2[tid];
    b3s[tid] = bs3[tid];

    if (tid < 128) {
        int e = e0 + tid;
        xyb[tid * 2] = el[e * 3]; xyb[tid * 2 + 1] = el[e * 3 + 1];
    }
    for (int i = 0; i < 4; ++i) {
        int cid = i * 256 + tid;
        int row = cid >> 3, c5 = cid & 7;
        short8 v = *(const short8*)(const void*)&w2h[row * 64 + c5 * 8];
        *(short8*)(void*)&w2t[row * 64 + ((c5 ^ (row & 7)) * 8)] = v;
    }
    for (int i = 0; i < 16; ++i) {
        int cid = i * 256 + tid;
        int row = cid >> 4, c5 = cid & 15;
        short8 v = *(const short8*)(const void*)&w3h[row * 128 + c5 * 8];
        *(short8*)(void*)&w3t[row * 128 + ((c5 ^ (row & 7)) * 8)] = v;
    }
    __syncthreads();

    // L1
    {
        int n = tid & 127;
        int j0 = (tid >> 7) * 32;
        float xx = xyb[n * 2], yy = xyb[n * 2 + 1];
        for (int jj = 0; jj < 32; ++jj) {
            int j = j0 + jj;
            float h = sigm(xx * s1w[j] + yy * s1w[64 + j] + b1s[j]);
            h1t[n * 64 + (((j >> 3) ^ (n & 7)) * 8) + (j & 7)] = f2bf(h);
        }
    }
    __syncthreads();

    // L2: (128x64)@(64x128)
    {
        const int mr = (wv >> 1) * 64;
        const int nc = (wv & 1) * 64;
        f32x4 acc[4][4];
        for (int m = 0; m < 4; ++m) for (int nf = 0; nf < 4; ++nf) acc[m][nf] = (f32x4){0.f, 0.f, 0.f, 0.f};
        for (int kk = 0; kk < 2; ++kk) {
            int kc = kk * 4 + (ln >> 4);
            short8 af[4], bf[4];
            for (int m = 0; m < 4; ++m) {
                int row = mr + 16 * m + (ln & 15);
                af[m] = *(const short8*)(const void*)&h1t[row * 64 + ((kc ^ (row & 7)) * 8)];
            }
            for (int nf = 0; nf < 4; ++nf) {
                int c = nc + 16 * nf + (ln & 15);
                bf[nf] = *(const short8*)(const void*)&w2t[c * 64 + ((kc ^ (c & 7)) * 8)];
            }
            for (int m = 0; m < 4; ++m)
                for (int nf = 0; nf < 4; ++nf)
                    acc[m][nf] = __builtin_amdgcn_mfma_f32_16x16x32_bf16(af[m], bf[nf], acc[m][nf], 0, 0, 0);
        }
        for (int m = 0; m < 4; ++m)
            for (int nf = 0; nf < 4; ++nf) {
                int c = nc + 16 * nf + (ln & 15);
                float bb = b2s[c];
                for (int r = 0; r < 4; ++r) {
                    int n = mr + 16 * m + (ln >> 4) * 4 + r;
                    float hh = sigm(acc[m][nf][r] + bb);
                    h2t[n * 128 + (((c >> 3) ^ (n & 7)) * 8) + (c & 7)] = f2bf(hh);
                }
            }
    }
    __syncthreads();

    // L3: (128x128)@(128x256)
    f32x4 acc3[4][8];
    const int mr3 = (wv >> 1) * 64;
    const int nc3 = (wv & 1) * 128;
    for (int m = 0; m < 4; ++m) for (int nf = 0; nf < 8; ++nf) acc3[m][nf] = (f32x4){0.f, 0.f, 0.f, 0.f};
    for (int kk = 0; kk < 4; ++kk) {
        int kc = kk * 4 + (ln >> 4);
        short8 af[4];
        for (int m = 0; m < 4; ++m) {
            int row = mr3 + 16 * m + (ln & 15);
            af[m] = *(const short8*)(const void*)&h2t[row * 128 + ((kc ^ (row & 7)) * 8)];
        }
        for (int nf = 0; nf < 8; ++nf) {
            int c = nc3 + 16 * nf + (ln & 15);
            short8 bf = *(const short8*)(const void*)&w3t[c * 128 + ((kc ^ (c & 7)) * 8)];
            for (int m = 0; m < 4; ++m)
                acc3[m][nf] = __builtin_amdgcn_mfma_f32_16x16x32_bf16(af[m], bf, acc3[m][nf], 0, 0, 0);
        }
    }
    __syncthreads();
    for (int m = 0; m < 4; ++m)
        for (int nf = 0; nf < 8; ++nf) {
            int c = nc3 + 16 * nf + (ln & 15);
            float bb = b3s[c];
            for (int r = 0; r < 4; ++r) {
                int n = mr3 + 16 * m + (ln >> 4) * 4 + r;
                float ss = sigm(acc3[m][nf][r] + bb);
                bufA[n * 256 + (((c >> 3) ^ (n & 7)) * 8) + (c & 7)] = f2bf(ss);
            }
        }
    __syncthreads();
    // linear coalesced copy-out
    for (int i = 0; i < 16; ++i) {
        int cid = i * 256 + tid;
        int row = cid >> 5, c5 = cid & 31;
        short8 v = *(const short8*)(const void*)&bufA[row * 256 + ((c5 ^ (row & 7)) * 8)];
        *(short8*)(void*)&s3h[(size_t)(e0 + row) * 256 + c5 * 8] = v;
    }
}

// ---------- phase B: bucket-group owner blocks; NO global atomics ----------
__global__ __launch_bounds__(256, 1) void k_sipm(
    const float* __restrict__ el, const float* __restrict__ wt,
    const float* __restrict__ bs4, const float* __restrict__ sis,
    const float* __restrict__ Wp1, const float* __restrict__ bp1,
    const float* __restrict__ Wp2, const float* __restrict__ bp2,
    const float* __restrict__ psc,
    const bfu* __restrict__ s3h, const bfu* __restrict__ w4h,
    const int* __restrict__ idxl, const int* __restrict__ counts,
    const int* __restrict__ offs,
    float* __restrict__ outP, float* __restrict__ outS) {

    __shared__ __align__(16) bfu w4t[64 * 256];    // [s][k] swz (32K)
    __shared__ __align__(16) bfu s3t[64 * 256];    // [n][k] swz (32K)
    __shared__ __align__(16) bfu rpt[64 * 64];     // [s][n] swz (8K)
    __shared__ __align__(16) bfu Et[16 * 64];      // [t][n] swz (2K)
    __shared__ __align__(16) bfu rpp[16 * 64];     // [p][n] swz (2K)
    __shared__ float accT[64 * 65];                // [tl][s] (16.6K)
    __shared__ float accP[64 * 13];                // [tl][p] (3.3K)
    __shared__ float pwb[448];
    __shared__ int idxb[64];
    __shared__ float xbv[64], ybv[64], zbv[64], wbv[64];
    __shared__ float bss[64], si2[64];

    const int tid = threadIdx.x;
    const int wv = tid >> 6, ln = tid & 63;
    const int bid = blockIdx.x;
    const int st  = bid % NSTILE;
    const int grp = (bid / NSTILE) % NGRP;
    const int b   = bid / (NSTILE * NGRP);
    const int bk0 = grp * GBK;
    const int bk1 = (bk0 + GBK < NBK) ? bk0 + GBK : NBK;
    const int T_lo = bk0 * 8 - 2;                  // owned tg in [max(T_lo,0), T_lo+64)
    const int s0 = st * 64;
    const bool do_pmt = (st == 0);

    for (int i = 0; i < 8; ++i) {                  // stage w4t once per block
        int cid = i * 256 + tid;
        int row = cid >> 5, c5 = cid & 31;
        short8 v = *(const short8*)(const void*)&w4h[(size_t)(s0 + row) * 256 + c5 * 8];
        *(short8*)(void*)&w4t[row * 256 + ((c5 ^ (row & 7)) * 8)] = v;
    }
    if (tid < 64) {
        int s = s0 + tid;
        bss[tid] = (s < NS) ? bs4[s] : 0.0f;
        float sc = (s < NS) ? sis[s] : 0.0f;
        si2[tid] = sc * sc;
    }
    if (do_pmt) {
        for (int i = tid; i < 444; i += 256)
            pwb[i] = (i < 56) ? Wp1[i] : (i < 84) ? bp1[i - 56] :
                     (i < 420) ? Wp2[i - 84] : (i < 432) ? bp2[i - 420] : psc[i - 432];
        {   // zero rpp rows 12..15 (read by GEMM2 B-cols 12..15, results discarded)
            int p = 12 + (tid >> 6), n = tid & 63;
            rpp[p * 64 + (((n >> 3) ^ (p & 7)) * 8) + (n & 7)] = 0;
        }
    }
    for (int i = tid; i < 64 * 65; i += 256) accT[i] = 0.f;
    for (int i = tid; i < 64 * 13; i += 256) accP[i] = 0.f;
    // first accT/rpp consumption is after >=2 barriers below

    for (int bk = (bk0 > 0 ? bk0 - 1 : 0); bk < bk1; ++bk) {
        const int key = b * NBK + bk;
        const int cnt = counts[key];                // block-uniform
        if (cnt == 0) continue;
        const int off = offs[key];
        const int db8 = (bk - bk0) * 8;

        f32x4 a2  = (f32x4){0.f, 0.f, 0.f, 0.f};
        f32x4 a2p = (f32x4){0.f, 0.f, 0.f, 0.f};

        const int nch = (cnt + 63) >> 6;
        for (int c = 0; c < nch; ++c) {
            __syncthreads();                        // prev GEMM2 reads done before restage
            if (tid < 64) {
                int li = c * 64 + tid;
                int e = (li < cnt) ? idxl[off + li] : -1;
                idxb[tid] = e;
                int eg = (e >= 0) ? e : 0;
                xbv[tid] = el[eg * 3]; ybv[tid] = el[eg * 3 + 1];
                zbv[tid] = (e >= 0) ? el[eg * 3 + 2] : 0.0f;
                wbv[tid] = (e >= 0) ? wt[eg] : 0.0f;
            }
            __syncthreads();                        // idxb/zbv ready
            for (int i = 0; i < 8; ++i) {           // stage s3 chunk (gather rows)
                int cid = i * 256 + tid;
                int row = cid >> 5, c5 = cid & 31;
                int e = idxb[row]; e = (e >= 0) ? e : 0;
                short8 v = *(const short8*)(const void*)&s3h[(size_t)e * 256 + c5 * 8];
                *(short8*)(void*)&s3t[row * 256 + ((c5 ^ (row & 7)) * 8)] = v;
            }
            {                                       // gaussian tile, owned-window masked
                int n = tid & 63;
                for (int i = 0; i < 4; ++i) {
                    int jj = i * 4 + (tid >> 6);
                    int tg = bk * 8 - 4 + jj;
                    int tl = tg - T_lo;
                    float d = (float)tg + 0.5f - zbv[n];
                    bool ok = (tg >= 0) && (tg < NT) && (tl >= 0) && (tl < 64);
                    float g = ok ? wbv[n] * GNRM * __expf(-10.0f * d * d) : 0.0f;
                    Et[jj * 64 + (((n >> 3) ^ (jj & 7)) * 8) + (n & 7)] = f2bf(g);
                }
            }
            if (do_pmt) {                           // pmt MLP for this chunk's electrons
                int n = tid & 63, pg = tid >> 6;
                float xx = xbv[n], yy = ybv[n];
                float hh[28];
                for (int j = 0; j < 28; ++j)
                    hh[j] = sigm(xx * pwb[j] + yy * pwb[28 + j] + pwb[56 + j]);
                for (int q = 0; q < 3; ++q) {
                    int p = pg * 3 + q;
                    float a = pwb[420 + p];
                    for (int j = 0; j < 28; ++j) a += hh[j] * pwb[84 + j * 12 + p];
                    float sc = pwb[432 + p];
                    float rp = sigm(a) * sc * sc;
                    rpp[p * 64 + (((n >> 3) ^ (p & 7)) * 8) + (n & 7)] = f2bf(rp);
                }
            }
            // GEMM1: (64n x 256k) @ (256k x 64s), wave owns 16 s
            f32x4 acc[4];
            for (int m = 0; m < 4; ++m) acc[m] = (f32x4){0.f, 0.f, 0.f, 0.f};
            {
                const int sl = 16 * wv + (ln & 15);
                for (int kk = 0; kk < 8; ++kk) {
                    int kc = kk * 4 + (ln >> 4);
                    short8 bf = *(const short8*)(const void*)&w4t[sl * 256 + ((kc ^ (sl & 7)) * 8)];
                    for (int m = 0; m < 4; ++m) {
                        int row = 16 * m + (ln & 15);
                        short8 af = *(const short8*)(const void*)&s3t[row * 256 + ((kc ^ (row & 7)) * 8)];
                        acc[m] = __builtin_amdgcn_mfma_f32_16x16x32_bf16(af, bf, acc[m], 0, 0, 0);
                    }
                }
                // sigmoid*scale^2 -> rpt[s][n]
                float bb = bss[sl], sc = si2[sl];
                for (int m = 0; m < 4; ++m) {
                    short4v pk;
                    for (int r = 0; r < 4; ++r)
                        pk[r] = (short)f2bf(sc * sigm(acc[m][r] + bb));
                    int n0 = 16 * m + (ln >> 4) * 4;
                    *(short4v*)(void*)&rpt[sl * 64 + (((n0 >> 3) ^ (sl & 7)) * 8) + (n0 & 7)] = pk;
                }
            }
            __syncthreads();                        // Et/rpt/rpp ready
            // GEMM2: a2 += E^T(16t x 64n) @ rpt^T; pmt (wave 0 only): a2p += E^T @ rpp^T
            {
                const int sl = 16 * wv + (ln & 15);
                const int tr = ln & 15;
                for (int kk = 0; kk < 2; ++kk) {
                    int kc = kk * 4 + (ln >> 4);
                    short8 ea = *(const short8*)(const void*)&Et[tr * 64 + ((kc ^ (tr & 7)) * 8)];
                    short8 bb = *(const short8*)(const void*)&rpt[sl * 64 + ((kc ^ (sl & 7)) * 8)];
                    a2 = __builtin_amdgcn_mfma_f32_16x16x32_bf16(ea, bb, a2, 0, 0, 0);
                    if (do_pmt && wv == 0) {
                        int p = ln & 15;
                        short8 bp = *(const short8*)(const void*)&rpp[p * 64 + ((kc ^ (p & 7)) * 8)];
                        a2p = __builtin_amdgcn_mfma_f32_16x16x32_bf16(ea, bp, a2p, 0, 0, 0);
                    }
                }
            }
        } // chunks

        // bucket accumulation into LDS (wave-disjoint sl for accT; wave0-only accP)
        {
            const int sl = 16 * wv + (ln & 15);
            for (int r = 0; r < 4; ++r) {
                int tl = db8 - 2 + (ln >> 4) * 4 + r;   // tg = 8bk-4+trow
                if (tl >= 0 && tl < 64) accT[tl * 65 + sl] += a2[r];
            }
        }
        if (do_pmt && wv == 0) {
            int p = ln & 15;
            if (p < 12)
                for (int r = 0; r < 4; ++r) {
                    int tl = db8 - 2 + (ln >> 4) * 4 + r;
                    if (tl >= 0 && tl < 64) accP[tl * 13 + p] += a2p[r];
                }
        }
    } // buckets

    __syncthreads();
    // flush owned window: plain coalesced stores (exact partition of [0,NT))
    for (int i = 0; i < 16; ++i) {
        int id = i * 256 + tid;
        int s = id >> 6, tl = id & 63;
        int tg = T_lo + tl;
        int sg = s0 + s;
        if (tg >= 0 && tg < NT && sg < NS)
            outS[((size_t)b * NS + sg) * NT + tg] = accT[tl * 65 + s];
    }
    if (do_pmt) {
        for (int i = tid; i < 64 * 12; i += 256) {
            int tl = i / 12, p = i % 12;
            int tg = T_lo + tl;
            if (tg >= 0 && tg < NT)
                outP[((size_t)b * NP + p) * NT + tg] = accP[tl * 13 + p];
        }
    }
}

extern "C" void kernel_launch(void* const* d_in, const int* in_sizes, int n_in,
                              void* d_out, int out_size, void* d_ws, size_t ws_size,
                              hipStream_t stream) {
    const float* el  = (const float*)d_in[0];
    const float* wt  = (const float*)d_in[1];
    const float* Wp1 = (const float*)d_in[2];
    const float* bp1 = (const float*)d_in[3];
    const float* Wp2 = (const float*)d_in[4];
    const float* bp2 = (const float*)d_in[5];
    const float* psc = (const float*)d_in[6];
    const float* Ws1 = (const float*)d_in[7];
    const float* bs1 = (const float*)d_in[8];
    const float* Ws2 = (const float*)d_in[9];
    const float* bs2 = (const float*)d_in[10];
    const float* Ws3 = (const float*)d_in[11];
    const float* bs3 = (const float*)d_in[12];
    const float* Ws4 = (const float*)d_in[13];
    const float* bs4 = (const float*)d_in[14];
    const float* sis = (const float*)d_in[15];
    float* out = (float*)d_out;

    // workspace layout identical to R2 (proven within ws_size)
    char* ws = (char*)d_ws;
    bfu* w2h     = (bfu*)(ws);                    // 16384
    bfu* w3h     = (bfu*)(ws + 16384);            // 65536
    bfu* w4h     = (bfu*)(ws + 81920);            // 1179648
    bfu* s3h     = (bfu*)(ws + 1261568);          // 16777216
    int* counts  = (int*)(ws + 18038784);
    int* offs    = (int*)(ws + 18042880);
    int* cursors = (int*)(ws + 18046976);
    int* idxl    = (int*)(ws + 18051072);         // 131072 -> end 18182144

    hipMemsetAsync(out, 0, (size_t)out_size * 4, stream);
    hipMemsetAsync(counts, 0, 4096, stream);
    hipMemsetAsync(cursors, 0, 4096, stream);

    k_prep<<<2464, 256, 0, stream>>>(Ws2, Ws3, Ws4, w2h, w3h, w4h);
    k_count<<<128, 256, 0, stream>>>(el, counts);
    k_scan<<<1, 64, 0, stream>>>(counts, offs);
    k_scatter<<<128, 256, 0, stream>>>(el, offs, cursors, idxl);
    k_mlp<<<256, 256, 0, stream>>>(el, Ws1, bs1, bs2, bs3, w2h, w3h, s3h);
    k_sipm<<<4 * NGRP * NSTILE, 256, 0, stream>>>(el, wt, bs4, sis, Wp1, bp1, Wp2, bp2, psc,
                                                  s3h, w4h, idxl, counts, offs,
                                                  out, out + 4 * NP * NT);
}

// Round 5
// 292.330 us; speedup vs baseline: 2.3103x; 1.3644x over previous
//
#include <hip/hip_runtime.h>

typedef short short8 __attribute__((ext_vector_type(8)));
typedef short short4v __attribute__((ext_vector_type(4)));
typedef float f32x4 __attribute__((ext_vector_type(4)));

#define NT 550
#define NS 2209
#define NP 12
#define NBK 69
#define NSTILE 18
#define NGRP 9
#define GBK 8
#define GNRM 3.9894228040143f

typedef unsigned short bfu;

__device__ __forceinline__ bfu f2bf(float f) {
    unsigned int u = __float_as_uint(f);
    unsigned int r = (u + 0x7fffu + ((u >> 16) & 1u)) >> 16;
    return (bfu)r;
}

__device__ __forceinline__ float sigm(float x) {
    return __builtin_amdgcn_rcpf(1.0f + __expf(-x));
}

// ---------- weight conversion: fp32 -> transposed bf16 ----------
__global__ void k_prep(const float* __restrict__ W2, const float* __restrict__ W3,
                       const float* __restrict__ W4,
                       bfu* __restrict__ w2h, bfu* __restrict__ w3h, bfu* __restrict__ w4h) {
    int id = blockIdx.x * 256 + threadIdx.x;
    if (id < 8192) {                       // w2h[c][k]  c<128,k<64   from W2(64,128)
        int c = id >> 6, k = id & 63;
        w2h[id] = f2bf(W2[k * 128 + c]);
    } else if (id < 8192 + 32768) {        // w3h[c][k]  c<256,k<128  from W3(128,256)
        int j = id - 8192;
        int c = j >> 7, k = j & 127;
        w3h[j] = f2bf(W3[k * 256 + c]);
    } else {                               // w4h[s][k]  s<2304,k<256 from W4(256,2209)
        int j = id - 40960;
        int s = j >> 8, k = j & 255;
        w4h[j] = f2bf(s < NS ? W4[k * NS + s] : 0.0f);
    }
}

// ---------- bucketing ----------
__global__ void k_count(const float* __restrict__ el, int* __restrict__ counts) {
    int id = blockIdx.x * 256 + threadIdx.x;
    float z = el[id * 3 + 2];
    int bk = (int)(z * 0.125f);
    bk = bk < 0 ? 0 : (bk > NBK - 1 ? NBK - 1 : bk);
    atomicAdd(&counts[(id >> 13) * NBK + bk], 1);
}

// parallel exclusive scan over 276 entries (was: 1 thread x 276 dependent RTs)
__global__ void k_scan(const int* __restrict__ counts, int* __restrict__ offs) {
    __shared__ int a[512];
    int tid = threadIdx.x;
    int v = (tid < 4 * NBK) ? counts[tid] : 0;
    a[tid] = v;
    __syncthreads();
    for (int s = 1; s < 512; s <<= 1) {
        int t = (tid >= s) ? a[tid - s] : 0;
        __syncthreads();
        a[tid] += t;
        __syncthreads();
    }
    if (tid < 4 * NBK) offs[tid] = a[tid] - v;
}

__global__ void k_scatter(const float* __restrict__ el, const int* __restrict__ offs,
                          int* __restrict__ cur, int* __restrict__ idxl) {
    int id = blockIdx.x * 256 + threadIdx.x;
    float z = el[id * 3 + 2];
    int bk = (int)(z * 0.125f);
    bk = bk < 0 ? 0 : (bk > NBK - 1 ? NBK - 1 : bk);
    int key = (id >> 13) * NBK + bk;
    int pos = offs[key] + atomicAdd(&cur[key], 1);
    idxl[pos] = id;
}

// ---------- phase A: sipm MLP layers 1-3 -> s3h (linear, bf16) ----------
__global__ __launch_bounds__(256, 1) void k_mlp(
    const float* __restrict__ el,
    const float* __restrict__ Ws1, const float* __restrict__ bs1,
    const float* __restrict__ bs2, const float* __restrict__ bs3,
    const bfu* __restrict__ w2h, const bfu* __restrict__ w3h,
    bfu* __restrict__ s3h) {

    __shared__ __align__(16) bfu bufA[32768];
    __shared__ __align__(16) bfu w3t[32768];
    __shared__ float xyb[256];
    __shared__ float s1w[128];
    __shared__ float b1s[64], b2s[128], b3s[256];

    bfu* h1t = bufA;            // [n][64]
    bfu* w2t = bufA + 8192;     // [c][64]
    bfu* h2t = bufA + 16384;    // [n][128]

    const int tid = threadIdx.x;
    const int wv = tid >> 6, ln = tid & 63;
    const int e0 = blockIdx.x * 128;

    if (tid < 128) s1w[tid] = Ws1[tid];
    if (tid < 64) b1s[tid] = bs1[tid];
    if (tid < 128) b2s[tid] = bs2[tid];
    b3s[tid] = bs3[tid];

    if (tid < 128) {
        int e = e0 + tid;
        xyb[tid * 2] = el[e * 3]; xyb[tid * 2 + 1] = el[e * 3 + 1];
    }
    for (int i = 0; i < 4; ++i) {
        int cid = i * 256 + tid;
        int row = cid >> 3, c5 = cid & 7;
        short8 v = *(const short8*)(const void*)&w2h[row * 64 + c5 * 8];
        *(short8*)(void*)&w2t[row * 64 + ((c5 ^ (row & 7)) * 8)] = v;
    }
    for (int i = 0; i < 16; ++i) {
        int cid = i * 256 + tid;
        int row = cid >> 4, c5 = cid & 15;
        short8 v = *(const short8*)(const void*)&w3h[row * 128 + c5 * 8];
        *(short8*)(void*)&w3t[row * 128 + ((c5 ^ (row & 7)) * 8)] = v;
    }
    __syncthreads();

    // L1
    {
        int n = tid & 127;
        int j0 = (tid >> 7) * 32;
        float xx = xyb[n * 2], yy = xyb[n * 2 + 1];
        for (int jj = 0; jj < 32; ++jj) {
            int j = j0 + jj;
            float h = sigm(xx * s1w[j] + yy * s1w[64 + j] + b1s[j]);
            h1t[n * 64 + (((j >> 3) ^ (n & 7)) * 8) + (j & 7)] = f2bf(h);
        }
    }
    __syncthreads();

    // L2: (128x64)@(64x128)
    {
        const int mr = (wv >> 1) * 64;
        const int nc = (wv & 1) * 64;
        f32x4 acc[4][4];
        for (int m = 0; m < 4; ++m) for (int nf = 0; nf < 4; ++nf) acc[m][nf] = (f32x4){0.f, 0.f, 0.f, 0.f};
        for (int kk = 0; kk < 2; ++kk) {
            int kc = kk * 4 + (ln >> 4);
            short8 af[4], bf[4];
            for (int m = 0; m < 4; ++m) {
                int row = mr + 16 * m + (ln & 15);
                af[m] = *(const short8*)(const void*)&h1t[row * 64 + ((kc ^ (row & 7)) * 8)];
            }
            for (int nf = 0; nf < 4; ++nf) {
                int c = nc + 16 * nf + (ln & 15);
                bf[nf] = *(const short8*)(const void*)&w2t[c * 64 + ((kc ^ (c & 7)) * 8)];
            }
            for (int m = 0; m < 4; ++m)
                for (int nf = 0; nf < 4; ++nf)
                    acc[m][nf] = __builtin_amdgcn_mfma_f32_16x16x32_bf16(af[m], bf[nf], acc[m][nf], 0, 0, 0);
        }
        for (int m = 0; m < 4; ++m)
            for (int nf = 0; nf < 4; ++nf) {
                int c = nc + 16 * nf + (ln & 15);
                float bb = b2s[c];
                for (int r = 0; r < 4; ++r) {
                    int n = mr + 16 * m + (ln >> 4) * 4 + r;
                    float hh = sigm(acc[m][nf][r] + bb);
                    h2t[n * 128 + (((c >> 3) ^ (n & 7)) * 8) + (c & 7)] = f2bf(hh);
                }
            }
    }
    __syncthreads();

    // L3: (128x128)@(128x256)
    f32x4 acc3[4][8];
    const int mr3 = (wv >> 1) * 64;
    const int nc3 = (wv & 1) * 128;
    for (int m = 0; m < 4; ++m) for (int nf = 0; nf < 8; ++nf) acc3[m][nf] = (f32x4){0.f, 0.f, 0.f, 0.f};
    for (int kk = 0; kk < 4; ++kk) {
        int kc = kk * 4 + (ln >> 4);
        short8 af[4];
        for (int m = 0; m < 4; ++m) {
            int row = mr3 + 16 * m + (ln & 15);
            af[m] = *(const short8*)(const void*)&h2t[row * 128 + ((kc ^ (row & 7)) * 8)];
        }
        for (int nf = 0; nf < 8; ++nf) {
            int c = nc3 + 16 * nf + (ln & 15);
            short8 bf = *(const short8*)(const void*)&w3t[c * 128 + ((kc ^ (c & 7)) * 8)];
            for (int m = 0; m < 4; ++m)
                acc3[m][nf] = __builtin_amdgcn_mfma_f32_16x16x32_bf16(af[m], bf, acc3[m][nf], 0, 0, 0);
        }
    }
    __syncthreads();
    for (int m = 0; m < 4; ++m)
        for (int nf = 0; nf < 8; ++nf) {
            int c = nc3 + 16 * nf + (ln & 15);
            float bb = b3s[c];
            for (int r = 0; r < 4; ++r) {
                int n = mr3 + 16 * m + (ln >> 4) * 4 + r;
                float ss = sigm(acc3[m][nf][r] + bb);
                bufA[n * 256 + (((c >> 3) ^ (n & 7)) * 8) + (c & 7)] = f2bf(ss);
            }
        }
    __syncthreads();
    for (int i = 0; i < 16; ++i) {
        int cid = i * 256 + tid;
        int row = cid >> 5, c5 = cid & 31;
        short8 v = *(const short8*)(const void*)&bufA[row * 256 + ((c5 ^ (row & 7)) * 8)];
        *(short8*)(void*)&s3h[(size_t)(e0 + row) * 256 + c5 * 8] = v;
    }
}

// ---------- phase B: 512-thread owner blocks, ring accumulator, no atomics ----------
__global__ __launch_bounds__(512, 1) void k_sipm(
    const float* __restrict__ el, const float* __restrict__ wt,
    const float* __restrict__ bs4, const float* __restrict__ sis,
    const float* __restrict__ Wp1, const float* __restrict__ bp1,
    const float* __restrict__ Wp2, const float* __restrict__ bp2,
    const float* __restrict__ psc,
    const bfu* __restrict__ s3h, const bfu* __restrict__ w4h,
    const int* __restrict__ idxl, const int* __restrict__ counts,
    const int* __restrict__ offs,
    float* __restrict__ outP, float* __restrict__ outS) {

    __shared__ __align__(16) bfu w4t[128 * 256];   // [s][k] swz   65536
    __shared__ __align__(16) bfu s3t[64 * 256];    // [n][k] swz   32768
    __shared__ __align__(16) bfu rpt[128 * 64];    // [s][n] swz   16384
    __shared__ __align__(16) bfu Et[16 * 64];      // [t][n] swz    2048
    __shared__ __align__(16) bfu rpp[16 * 64];     // [p][n] swz    2048
    __shared__ float accT[16 * 129];               // ring [tl&15][s] 8256
    __shared__ float accP[64 * 12];                //               3072
    __shared__ float pwb[444];                     //               1776
    __shared__ int idxb[64];                       //                256
    __shared__ float4 elb[64];                     //               1024
    __shared__ float bss[128], si2[128];           //               1024
    // total ~134,192 B (<= proven 134,400)

    const int tid = threadIdx.x;
    const int wv = tid >> 6, ln = tid & 63;
    const int bid = blockIdx.x;
    const int st  = bid % NSTILE;
    const int grp = (bid / NSTILE) % NGRP;
    const int b   = bid / (NSTILE * NGRP);
    const int bk0 = grp * GBK;
    const int bk1 = (bk0 + GBK < NBK) ? bk0 + GBK : NBK;
    const int T_lo = bk0 * 8 - 2;                  // owned tg in [max(T_lo,0), T_lo+64)
    const int s0 = st * 128;
    const bool do_pmt = (st == 0);
    const int sl = 16 * wv + (ln & 15);            // this wave's s columns

    for (int i = 0; i < 8; ++i) {                  // stage w4t once per block
        int cid = i * 512 + tid;
        int row = cid >> 5, c5 = cid & 31;
        short8 v = *(const short8*)(const void*)&w4h[(size_t)(s0 + row) * 256 + c5 * 8];
        *(short8*)(void*)&w4t[row * 256 + ((c5 ^ (row & 7)) * 8)] = v;
    }
    if (tid < 128) {
        int s = s0 + tid;
        bss[tid] = (s < NS) ? bs4[s] : 0.0f;
        float sc = (s < NS) ? sis[s] : 0.0f;
        si2[tid] = sc * sc;
    }
    if (do_pmt) {
        if (tid < 444)
            pwb[tid] = (tid < 56) ? Wp1[tid] : (tid < 84) ? bp1[tid - 56] :
                       (tid < 420) ? Wp2[tid - 84] : (tid < 432) ? bp2[tid - 420] : psc[tid - 432];
        if (tid < 256) {   // zero rpp rows 12..15 (GEMM2 reads them; cols discarded)
            int p = 12 + (tid >> 6), n = tid & 63;
            rpp[p * 64 + (((n >> 3) ^ (p & 7)) * 8) + (n & 7)] = 0;
        }
    }
    for (int i = tid; i < 16 * 129; i += 512) accT[i] = 0.f;
    for (int i = tid; i < 64 * 12; i += 512) accP[i] = 0.f;
    __syncthreads();

    int F = 0;                                     // next unflushed tl row
    for (int bk = (bk0 > 0 ? bk0 - 1 : 0); bk < bk1; ++bk) {
        const int key = b * NBK + bk;
        const int cnt = counts[key];               // block-uniform
        const int off = offs[key];
        const int db8 = (bk - bk0) * 8;

        if (cnt > 0) {
            f32x4 a2  = (f32x4){0.f, 0.f, 0.f, 0.f};
            f32x4 a2p = (f32x4){0.f, 0.f, 0.f, 0.f};

            const int nch = (cnt + 63) >> 6;
            for (int c = 0; c < nch; ++c) {
                __syncthreads();                   // prev-chunk GEMM2 reads done before restage
                if (tid < 64) {
                    int li = c * 64 + tid;
                    int e = (li < cnt) ? idxl[off + li] : -1;
                    idxb[tid] = e;
                    int eg = (e >= 0) ? e : 0;
                    float4 v;
                    v.x = el[eg * 3]; v.y = el[eg * 3 + 1]; v.z = el[eg * 3 + 2];
                    v.w = (e >= 0) ? wt[eg] : 0.0f;
                    elb[tid] = v;
                }
                __syncthreads();                   // idxb/elb ready
                for (int i = 0; i < 4; ++i) {      // stage s3 chunk (gather rows)
                    int cid = i * 512 + tid;
                    int row = cid >> 5, c5 = cid & 31;
                    int e = idxb[row]; e = (e >= 0) ? e : 0;
                    short8 v = *(const short8*)(const void*)&s3h[(size_t)e * 256 + c5 * 8];
                    *(short8*)(void*)&s3t[row * 256 + ((c5 ^ (row & 7)) * 8)] = v;
                }
                for (int i = 0; i < 2; ++i) {      // gaussian tile, owned-window masked
                    int id = i * 512 + tid;
                    int jj = id >> 6, n = id & 63;
                    int tg = bk * 8 - 4 + jj;
                    int tl = tg - T_lo;
                    float d = (float)tg + 0.5f - elb[n].z;
                    bool ok = (tg >= 0) && (tg < NT) && (tl >= 0) && (tl < 64);
                    float g = ok ? elb[n].w * GNRM * __expf(-10.0f * d * d) : 0.0f;
                    Et[jj * 64 + (((n >> 3) ^ (jj & 7)) * 8) + (n & 7)] = f2bf(g);
                }
                if (do_pmt && wv < 6) {            // pmt MLP: waves 0-5, 2 p's each
                    int n = ln;
                    float xx = elb[n].x, yy = elb[n].y;
                    float hh[28];
                    for (int j = 0; j < 28; ++j)
                        hh[j] = sigm(xx * pwb[j] + yy * pwb[28 + j] + pwb[56 + j]);
                    for (int q = 0; q < 2; ++q) {
                        int p = wv * 2 + q;
                        float a = pwb[420 + p];
                        for (int j = 0; j < 28; ++j) a += hh[j] * pwb[84 + j * 12 + p];
                        float sc = pwb[432 + p];
                        float rp = sigm(a) * sc * sc;
                        rpp[p * 64 + (((n >> 3) ^ (p & 7)) * 8) + (n & 7)] = f2bf(rp);
                    }
                }
                __syncthreads();                   // RACE FIX: s3t/Et/rpp visible to all waves

                // GEMM1: (64n x 256k) @ (256k x 128s); wave owns 16 s
                f32x4 acc[4];
                for (int m = 0; m < 4; ++m) acc[m] = (f32x4){0.f, 0.f, 0.f, 0.f};
                for (int kk = 0; kk < 8; ++kk) {
                    int kc = kk * 4 + (ln >> 4);
                    short8 bf = *(const short8*)(const void*)&w4t[sl * 256 + ((kc ^ (sl & 7)) * 8)];
                    for (int m = 0; m < 4; ++m) {
                        int row = 16 * m + (ln & 15);
                        short8 af = *(const short8*)(const void*)&s3t[row * 256 + ((kc ^ (row & 7)) * 8)];
                        acc[m] = __builtin_amdgcn_mfma_f32_16x16x32_bf16(af, bf, acc[m], 0, 0, 0);
                    }
                }
                {                                  // sigmoid*scale^2 -> rpt (wave-private rows)
                    float bb = bss[sl], sc = si2[sl];
                    for (int m = 0; m < 4; ++m) {
                        short4v pk;
                        for (int r = 0; r < 4; ++r)
                            pk[r] = (short)f2bf(sc * sigm(acc[m][r] + bb));
                        int n0 = 16 * m + (ln >> 4) * 4;
                        *(short4v*)(void*)&rpt[sl * 64 + (((n0 >> 3) ^ (sl & 7)) * 8) + (n0 & 7)] = pk;
                    }
                }
                __syncthreads();                   // Et (cross-wave) ready for GEMM2
                {
                    const int tr = ln & 15;
                    for (int kk = 0; kk < 2; ++kk) {
                        int kc = kk * 4 + (ln >> 4);
                        short8 ea = *(const short8*)(const void*)&Et[tr * 64 + ((kc ^ (tr & 7)) * 8)];
                        short8 bb = *(const short8*)(const void*)&rpt[sl * 64 + ((kc ^ (sl & 7)) * 8)];
                        a2 = __builtin_amdgcn_mfma_f32_16x16x32_bf16(ea, bb, a2, 0, 0, 0);
                        if (do_pmt && wv == 0) {
                            int p = ln & 15;
                            short8 bp = *(const short8*)(const void*)&rpp[p * 64 + ((kc ^ (p & 7)) * 8)];
                            a2p = __builtin_amdgcn_mfma_f32_16x16x32_bf16(ea, bp, a2p, 0, 0, 0);
                        }
                    }
                }
            } // chunks

            // bucket accumulation into ring (wave-disjoint sl; accum rows >= F always)
            for (int r = 0; r < 4; ++r) {
                int tl = db8 - 2 + (ln >> 4) * 4 + r;
                if (tl >= 0 && tl < 64) accT[(tl & 15) * 129 + sl] += a2[r];
            }
            if (do_pmt && wv == 0) {
                int p = ln & 15;
                if (p < 12)
                    for (int r = 0; r < 4; ++r) {
                        int tl = db8 - 2 + (ln >> 4) * 4 + r;
                        if (tl >= 0 && tl < 64) accP[tl * 12 + p] += a2p[r];
                    }
            }
        } // cnt>0

        // incremental flush of finalized rows [F, Fn)
        int Fn = (bk == bk1 - 1) ? 64 : (db8 + 6);
        if (Fn > 64) Fn = 64;
        if (Fn > F) {
            __syncthreads();                       // all accum writes visible
            for (int i = tid; i < (Fn - F) * 128; i += 512) {
                int dr = i >> 7, s = i & 127;
                int tl = F + dr;
                int tg = T_lo + tl, sg = s0 + s;
                float v = accT[(tl & 15) * 129 + s];
                accT[(tl & 15) * 129 + s] = 0.f;   // free ring slot
                if (tg >= 0 && tg < NT && sg < NS)
                    outS[((size_t)b * NS + sg) * NT + tg] = v;
            }
            F = Fn;
        }
    } // buckets

    if (do_pmt) {
        __syncthreads();
        for (int i = tid; i < 64 * 12; i += 512) {
            int tl = i / 12, p = i % 12;
            int tg = T_lo + tl;
            if (tg >= 0 && tg < NT)
                outP[((size_t)b * NP + p) * NT + tg] = accP[tl * 12 + p];
        }
    }
}

extern "C" void kernel_launch(void* const* d_in, const int* in_sizes, int n_in,
                              void* d_out, int out_size, void* d_ws, size_t ws_size,
                              hipStream_t stream) {
    const float* el  = (const float*)d_in[0];
    const float* wt  = (const float*)d_in[1];
    const float* Wp1 = (const float*)d_in[2];
    const float* bp1 = (const float*)d_in[3];
    const float* Wp2 = (const float*)d_in[4];
    const float* bp2 = (const float*)d_in[5];
    const float* psc = (const float*)d_in[6];
    const float* Ws1 = (const float*)d_in[7];
    const float* bs1 = (const float*)d_in[8];
    const float* Ws2 = (const float*)d_in[9];
    const float* bs2 = (const float*)d_in[10];
    const float* Ws3 = (const float*)d_in[11];
    const float* bs3 = (const float*)d_in[12];
    const float* Ws4 = (const float*)d_in[13];
    const float* bs4 = (const float*)d_in[14];
    const float* sis = (const float*)d_in[15];
    float* out = (float*)d_out;

    // workspace layout byte-identical to R2/R4 (proven within ws_size)
    char* ws = (char*)d_ws;
    bfu* w2h     = (bfu*)(ws);                    // 16384
    bfu* w3h     = (bfu*)(ws + 16384);            // 65536
    bfu* w4h     = (bfu*)(ws + 81920);            // 1179648
    bfu* s3h     = (bfu*)(ws + 1261568);          // 16777216
    int* counts  = (int*)(ws + 18038784);
    int* offs    = (int*)(ws + 18042880);
    int* cursors = (int*)(ws + 18046976);
    int* idxl    = (int*)(ws + 18051072);         // 131072 -> end 18182144

    hipMemsetAsync(out, 0, (size_t)out_size * 4, stream);
    hipMemsetAsync(counts, 0, 4096, stream);
    hipMemsetAsync(cursors, 0, 4096, stream);

    k_prep<<<2464, 256, 0, stream>>>(Ws2, Ws3, Ws4, w2h, w3h, w4h);
    k_count<<<128, 256, 0, stream>>>(el, counts);
    k_scan<<<1, 512, 0, stream>>>(counts, offs);
    k_scatter<<<128, 256, 0, stream>>>(el, offs, cursors, idxl);
    k_mlp<<<256, 256, 0, stream>>>(el, Ws1, bs1, bs2, bs3, w2h, w3h, s3h);
    k_sipm<<<4 * NGRP * NSTILE, 512, 0, stream>>>(el, wt, bs4, sis, Wp1, bp1, Wp2, bp2, psc,
                                                  s3h, w4h, idxl, counts, offs,
                                                  out, out + 4 * NP * NT);
}